// Round 3
// baseline (746.083 us; speedup 1.0000x reference)
//
#include <hip/hip_runtime.h>
#include <math.h>

// Fused MoE, register-resident h:
//   gating MLP (fp32 VALU, LDS-cooperative) -> gates in LDS
//   16 experts on mfma_f32_32x32x16_bf16, h kept in registers as B-fragments
//   (hi/lo 2-term bf16 split), transposed between layers via permlane32_swap.
//   Zero barriers and zero LDS traffic in the expert phase.

#define N_TOK 65536
#define T_BLK 128
#define THREADS 256
// LDS: gating scratch gA/gB (2 x 32KB f32) + gates (8KB)
#define SMEM_BYTES 73728

typedef short bf16x8 __attribute__((ext_vector_type(8)));
typedef float f32x16 __attribute__((ext_vector_type(16)));

__device__ __forceinline__ float tanh_fast(float x) {
    float e = __expf(2.0f * x);
    return fmaf(-2.0f, __builtin_amdgcn_rcpf(e + 1.0f), 1.0f);
}

// (bf16(v0) low half) | (bf16(v1) high half), truncation split
__device__ __forceinline__ unsigned pack_hi_pair(float v0, float v1) {
    return (__float_as_uint(v0) >> 16) | (__float_as_uint(v1) & 0xffff0000u);
}
__device__ __forceinline__ float hi_part(float v) {
    return __uint_as_float(__float_as_uint(v) & 0xffff0000u);
}

// v_permlane32_swap_b32: d.upper32lanes <-> s.lower32lanes
__device__ __forceinline__ void lane32_swap(unsigned& d, unsigned& s) {
#if __has_builtin(__builtin_amdgcn_permlane32_swap)
    auto r = __builtin_amdgcn_permlane32_swap((int)d, (int)s, false, false);
    d = (unsigned)r[0];
    s = (unsigned)r[1];
#else
    unsigned pd = (unsigned)__shfl_xor((int)d, 32, 64);
    unsigned ps = (unsigned)__shfl_xor((int)s, 32, 64);
    bool up = (threadIdx.x & 32) != 0;
    unsigned nd = up ? ps : d;
    unsigned ns = up ? s : pd;
    d = nd; s = ns;
#endif
}

__device__ __forceinline__ bf16x8 mk8(unsigned a, unsigned b, unsigned c, unsigned d) {
    union { unsigned u[4]; bf16x8 v; } t;
    t.u[0] = a; t.u[1] = b; t.u[2] = c; t.u[3] = d;
    return t.v;
}

// ---------------- prep: pack ewm -> bf16 A-fragments for 32x32x16 ----------------
// layout: [el][jt(4)][ks(8)][lane(64)] x 16B ; elem u: row j = jt*32 + (lane&31),
// k = ks*16 + (lane>>5)*8 + u ; value = W[k][j] = ewm[el][k][j]  (RNE to bf16)
__launch_bounds__(256)
__global__ void pack_wm_kernel(const float* __restrict__ ewm,
                               unsigned short* __restrict__ wsA) {
    int t    = blockIdx.x * 256 + threadIdx.x;   // 48*4*8*64 = 98304
    int lane = t & 63;
    int ks   = (t >> 6) & 7;
    int jt   = (t >> 9) & 3;
    int el   = t >> 11;                          // 0..47
    int j    = jt * 32 + (lane & 31);
    int k0   = ks * 16 + (lane >> 5) * 8;
    const float* src = ewm + (size_t)el * 16384;
    unsigned short o[8];
#pragma unroll
    for (int u = 0; u < 8; ++u) {
        unsigned b = __float_as_uint(src[(k0 + u) * 128 + j]);
        b += 0x7fffu + ((b >> 16) & 1u);         // RNE to bf16
        o[u] = (unsigned short)(b >> 16);
    }
    uint4 v;
    v.x = (unsigned)o[0] | ((unsigned)o[1] << 16);
    v.y = (unsigned)o[2] | ((unsigned)o[3] << 16);
    v.z = (unsigned)o[4] | ((unsigned)o[5] << 16);
    v.w = (unsigned)o[6] | ((unsigned)o[7] << 16);
    *(uint4*)(wsA + (size_t)el * 16384 + (size_t)((jt * 8 + ks) * 64 + lane) * 8) = v;
}

// one expert mid layer: acc = W^T(A) x h(B) + bias; h' = tanh -> hi/lo -> swap
__device__ __forceinline__ void mid_layer(const uint4* __restrict__ A,
                                          const float* __restrict__ bias,
                                          int lane, int g2,
                                          const bf16x8 (&Bh)[8], const bf16x8 (&Bl)[8],
                                          bf16x8 (&Nh)[8], bf16x8 (&Nl)[8]) {
#pragma unroll
    for (int jt = 0; jt < 4; ++jt) {
        f32x16 acc;
#pragma unroll
        for (int qd = 0; qd < 4; ++qd) {
            const float4 bb = *(const float4*)(bias + jt * 32 + qd * 8 + g2 * 4);
            acc[4 * qd + 0] = bb.x; acc[4 * qd + 1] = bb.y;
            acc[4 * qd + 2] = bb.z; acc[4 * qd + 3] = bb.w;
        }
#pragma unroll
        for (int ks = 0; ks < 8; ++ks) {
            bf16x8 a = *(const bf16x8*)(A + (jt * 8 + ks) * 64 + lane);
            acc = __builtin_amdgcn_mfma_f32_32x32x16_bf16(a, Bh[ks], acc, 0, 0, 0);
            acc = __builtin_amdgcn_mfma_f32_32x32x16_bf16(a, Bl[ks], acc, 0, 0, 0);
        }
        float tv[16];
#pragma unroll
        for (int r = 0; r < 16; ++r) tv[r] = tanh_fast(acc[r]);
#pragma unroll
        for (int p = 0; p < 2; ++p) {
            unsigned ah0 = pack_hi_pair(tv[8 * p + 0], tv[8 * p + 1]);
            unsigned ah1 = pack_hi_pair(tv[8 * p + 2], tv[8 * p + 3]);
            unsigned bh0 = pack_hi_pair(tv[8 * p + 4], tv[8 * p + 5]);
            unsigned bh1 = pack_hi_pair(tv[8 * p + 6], tv[8 * p + 7]);
            float r0 = tv[8 * p + 0] - hi_part(tv[8 * p + 0]);
            float r1 = tv[8 * p + 1] - hi_part(tv[8 * p + 1]);
            float r2 = tv[8 * p + 2] - hi_part(tv[8 * p + 2]);
            float r3 = tv[8 * p + 3] - hi_part(tv[8 * p + 3]);
            float r4 = tv[8 * p + 4] - hi_part(tv[8 * p + 4]);
            float r5 = tv[8 * p + 5] - hi_part(tv[8 * p + 5]);
            float r6 = tv[8 * p + 6] - hi_part(tv[8 * p + 6]);
            float r7 = tv[8 * p + 7] - hi_part(tv[8 * p + 7]);
            unsigned al0 = pack_hi_pair(r0, r1);
            unsigned al1 = pack_hi_pair(r2, r3);
            unsigned bl0 = pack_hi_pair(r4, r5);
            unsigned bl1 = pack_hi_pair(r6, r7);
            // exchange odd/even quads across the lane^32 pair
            lane32_swap(ah0, bh0); lane32_swap(ah1, bh1);
            lane32_swap(al0, bl0); lane32_swap(al1, bl1);
            Nh[2 * jt + p] = mk8(ah0, ah1, bh0, bh1);
            Nl[2 * jt + p] = mk8(al0, al1, bl0, bl1);
        }
    }
}

__launch_bounds__(THREADS, 2)
__global__ void moe_fused(const float* __restrict__ x,
                          const float* __restrict__ ew1,
                          const float* __restrict__ eb1,
                          const float* __restrict__ ewm,   // unused (prepacked)
                          const float* __restrict__ ebm,
                          const float* __restrict__ ewo,
                          const float* __restrict__ ebo,
                          const float* __restrict__ gw1,
                          const float* __restrict__ gb1,
                          const float* __restrict__ gwm,
                          const float* __restrict__ gbm,
                          const float* __restrict__ gwo,
                          const float* __restrict__ gbo,
                          const uint4* __restrict__ wsA,
                          float* __restrict__ y) {
    extern __shared__ char smem[];
    float* gates_l = (float*)(smem + 65536);     // [16][128]

    const int tid = threadIdx.x;
    const int blk = blockIdx.x;

    // ================= gating (fp32 VALU, LDS-cooperative) =================
    {
        const int tk = tid & 127;
        const int q  = tid >> 7;                 // 0/1, wave-uniform
        const int j0 = q * 32;
        float* gA = (float*)smem;                // [64][128]
        float* gB = gA + 8192;
        const float gx0 = x[(blk * T_BLK + tk) * 2 + 0];
        const float gx1 = x[(blk * T_BLK + tk) * 2 + 1];
#pragma unroll
        for (int m = 0; m < 32; ++m) {
            int j = j0 + m;
            float pre = fmaf(gx0, gw1[j], fmaf(gx1, gw1[64 + j], gb1[j]));
            gA[j * 128 + tk] = tanh_fast(pre);
        }
        __syncthreads();
#pragma unroll 1
        for (int l = 0; l < 2; ++l) {
            const float* gin  = l ? gB : gA;
            float*       gout = l ? gA : gB;
            const float* w  = gwm + l * 4096;
            const float* bb = gbm + l * 64;
            float acc[32];
#pragma unroll
            for (int m = 0; m < 32; ++m) acc[m] = bb[j0 + m];
#pragma unroll 4
            for (int k = 0; k < 64; ++k) {
                float gv = gin[k * 128 + tk];
                const float* wr = w + k * 64 + j0;
#pragma unroll
                for (int m = 0; m < 32; ++m) acc[m] = fmaf(gv, wr[m], acc[m]);
            }
#pragma unroll
            for (int m = 0; m < 32; ++m) gout[(j0 + m) * 128 + tk] = tanh_fast(acc[m]);
            __syncthreads();
        }
        // logits: q-group computes experts q*8..q*8+7 ; g is in gA
        float lg[8];
#pragma unroll
        for (int m = 0; m < 8; ++m) lg[m] = gbo[q * 8 + m];
#pragma unroll 4
        for (int k = 0; k < 64; ++k) {
            float gv = gA[k * 128 + tk];
            const float* wr = gwo + k * 16 + q * 8;
#pragma unroll
            for (int m = 0; m < 8; ++m) lg[m] = fmaf(gv, wr[m], lg[m]);
        }
        const float FIVE_PI = 15.707963267948966f;
#pragma unroll
        for (int m = 0; m < 8; ++m)
            gates_l[(q * 8 + m) * 128 + tk] = __sinf(FIVE_PI * lg[m]);
        __syncthreads();   // last barrier; expert phase is barrier-free
    }

    // ================= experts: h in registers as B-fragments =================
    const int lane = tid & 63;
    const int w_id = tid >> 6;       // 0..3
    const int t    = lane & 31;      // token within wave tile
    const int g2   = lane >> 5;      // k-half / j-bit3 owner
    const int wtok = w_id * 32 + t;
    const float ex0 = x[(blk * T_BLK + wtok) * 2 + 0];
    const float ex1 = x[(blk * T_BLK + wtok) * 2 + 1];
    float yacc = 0.0f;

    bf16x8 Bh[8], Bl[8], Nh[8], Nl[8];

#pragma unroll 1
    for (int e = 0; e < 16; ++e) {
        // ---- EL1: 2 -> 128, directly into B-fragment layout ----
        {
            const float* w1 = ew1 + e * 256;
            const float* b1 = eb1 + e * 128;
#pragma unroll
            for (int ks = 0; ks < 8; ++ks) {
                int j8 = ks * 16 + g2 * 8;
                const float4 wa0 = *(const float4*)(w1 + j8);
                const float4 wa1 = *(const float4*)(w1 + j8 + 4);
                const float4 wb0 = *(const float4*)(w1 + 128 + j8);
                const float4 wb1 = *(const float4*)(w1 + 128 + j8 + 4);
                const float4 bb0 = *(const float4*)(b1 + j8);
                const float4 bb1 = *(const float4*)(b1 + j8 + 4);
                float t0 = tanh_fast(fmaf(ex0, wa0.x, fmaf(ex1, wb0.x, bb0.x)));
                float t1 = tanh_fast(fmaf(ex0, wa0.y, fmaf(ex1, wb0.y, bb0.y)));
                float t2 = tanh_fast(fmaf(ex0, wa0.z, fmaf(ex1, wb0.z, bb0.z)));
                float t3 = tanh_fast(fmaf(ex0, wa0.w, fmaf(ex1, wb0.w, bb0.w)));
                float t4 = tanh_fast(fmaf(ex0, wa1.x, fmaf(ex1, wb1.x, bb1.x)));
                float t5 = tanh_fast(fmaf(ex0, wa1.y, fmaf(ex1, wb1.y, bb1.y)));
                float t6 = tanh_fast(fmaf(ex0, wa1.z, fmaf(ex1, wb1.z, bb1.z)));
                float t7 = tanh_fast(fmaf(ex0, wa1.w, fmaf(ex1, wb1.w, bb1.w)));
                unsigned h0 = pack_hi_pair(t0, t1), h1 = pack_hi_pair(t2, t3);
                unsigned h2 = pack_hi_pair(t4, t5), h3 = pack_hi_pair(t6, t7);
                float r0 = t0 - hi_part(t0), r1 = t1 - hi_part(t1);
                float r2 = t2 - hi_part(t2), r3 = t3 - hi_part(t3);
                float r4 = t4 - hi_part(t4), r5 = t5 - hi_part(t5);
                float r6 = t6 - hi_part(t6), r7 = t7 - hi_part(t7);
                Bh[ks] = mk8(h0, h1, h2, h3);
                Bl[ks] = mk8(pack_hi_pair(r0, r1), pack_hi_pair(r2, r3),
                             pack_hi_pair(r4, r5), pack_hi_pair(r6, r7));
            }
        }
        // ---- 3 mid layers (128x128 MFMA each), h stays in registers ----
        {
            const uint4* A0 = wsA + (size_t)(e * 3 + 0) * 2048;
            mid_layer(A0, ebm + (e * 3 + 0) * 128, lane, g2, Bh, Bl, Nh, Nl);
#pragma unroll
            for (int k = 0; k < 8; ++k) { Bh[k] = Nh[k]; Bl[k] = Nl[k]; }
            const uint4* A1 = wsA + (size_t)(e * 3 + 1) * 2048;
            mid_layer(A1, ebm + (e * 3 + 1) * 128, lane, g2, Bh, Bl, Nh, Nl);
#pragma unroll
            for (int k = 0; k < 8; ++k) { Bh[k] = Nh[k]; Bl[k] = Nl[k]; }
            const uint4* A2 = wsA + (size_t)(e * 3 + 2) * 2048;
            mid_layer(A2, ebm + (e * 3 + 2) * 128, lane, g2, Bh, Bl, Nh, Nl);
#pragma unroll
            for (int k = 0; k < 8; ++k) { Bh[k] = Nh[k]; Bl[k] = Nl[k]; }
        }
        // ---- output dot: eo = h3 . ewo[e] + ebo[e] ----
        {
            float ps = 0.0f;
            const float* wo = ewo + e * 128;
#pragma unroll
            for (int ks = 0; ks < 8; ++ks) {
                int j8 = ks * 16 + g2 * 8;
                const float4 w0 = *(const float4*)(wo + j8);
                const float4 w1v = *(const float4*)(wo + j8 + 4);
                union { bf16x8 v; unsigned u[4]; } H, L;
                H.v = Bh[ks]; L.v = Bl[ks];
                float e0 = __uint_as_float(H.u[0] << 16) + __uint_as_float(L.u[0] << 16);
                float e1 = __uint_as_float(H.u[0] & 0xffff0000u) + __uint_as_float(L.u[0] & 0xffff0000u);
                float e2 = __uint_as_float(H.u[1] << 16) + __uint_as_float(L.u[1] << 16);
                float e3 = __uint_as_float(H.u[1] & 0xffff0000u) + __uint_as_float(L.u[1] & 0xffff0000u);
                float e4 = __uint_as_float(H.u[2] << 16) + __uint_as_float(L.u[2] << 16);
                float e5 = __uint_as_float(H.u[2] & 0xffff0000u) + __uint_as_float(L.u[2] & 0xffff0000u);
                float e6 = __uint_as_float(H.u[3] << 16) + __uint_as_float(L.u[3] << 16);
                float e7 = __uint_as_float(H.u[3] & 0xffff0000u) + __uint_as_float(L.u[3] & 0xffff0000u);
                ps = fmaf(e0, w0.x, ps);  ps = fmaf(e1, w0.y, ps);
                ps = fmaf(e2, w0.z, ps);  ps = fmaf(e3, w0.w, ps);
                ps = fmaf(e4, w1v.x, ps); ps = fmaf(e5, w1v.y, ps);
                ps = fmaf(e6, w1v.z, ps); ps = fmaf(e7, w1v.w, ps);
            }
            ps += __shfl_xor(ps, 32, 64);        // combine g2 halves
            float eo = ps + ebo[e];
            yacc = fmaf(gates_l[e * 128 + wtok], eo, yacc);
        }
    }

    if (lane < 32) y[blk * T_BLK + wtok] = yacc;
}

extern "C" void kernel_launch(void* const* d_in, const int* in_sizes, int n_in,
                              void* d_out, int out_size, void* d_ws, size_t ws_size,
                              hipStream_t stream) {
    const float* x   = (const float*)d_in[0];
    const float* ew1 = (const float*)d_in[1];
    const float* eb1 = (const float*)d_in[2];
    const float* ewm = (const float*)d_in[3];
    const float* ebm = (const float*)d_in[4];
    const float* ewo = (const float*)d_in[5];
    const float* ebo = (const float*)d_in[6];
    const float* gw1 = (const float*)d_in[7];
    const float* gb1 = (const float*)d_in[8];
    const float* gwm = (const float*)d_in[9];
    const float* gbm = (const float*)d_in[10];
    const float* gwo = (const float*)d_in[11];
    const float* gbo = (const float*)d_in[12];
    float* y = (float*)d_out;
    unsigned short* wsA = (unsigned short*)d_ws;   // 48*32KB = 1.5MB bf16 A-frags

    pack_wm_kernel<<<384, 256, 0, stream>>>(ewm, wsA);

    hipFuncSetAttribute((const void*)moe_fused,
                        hipFuncAttributeMaxDynamicSharedMemorySize, SMEM_BYTES);
    moe_fused<<<dim3(N_TOK / T_BLK), dim3(THREADS), SMEM_BYTES, stream>>>(
        x, ew1, eb1, ewm, ebm, ewo, ebo, gw1, gb1, gwm, gbm, gwo, gbo,
        (const uint4*)wsA, y);
}

// Round 4
// 476.607 us; speedup vs baseline: 1.5654x; 1.5654x over previous
//
#include <hip/hip_runtime.h>
#include <hip/hip_bf16.h>
#include <math.h>

// Fused MoE, round 4: expert-split waves for 2x TLP.
//  - 1024 blocks x 256 thr (4 waves). Wave = (tile = w_id>>1, ehalf = w_id&1).
//  - Each wave: 32 tokens, 8 experts (ehalf*8..+7), h in registers as
//    32x32x16 MFMA B-fragments (hi/lo bf16 split), W A-frags read global->reg
//    (L2-resident, prepacked by pack kernel into d_ws).
//  - Gating fully in-register via MFMA (3-term hi/lo), ehalf0 wave only,
//    gates passed via 4KB LDS table. Final cross-wave combine via 256B LDS.
//  - No barriers except 2 (post-gating, pre-combine).

#define N_TOK 65536
#define T_BLK 64
#define THREADS 256

#define EXP_U4   0        // experts: 48 layers * 2048 uint4 (32KB each)
#define GMID_U4  98304    // gating mid: (l*2+hl)*512 + (jt*4+ks)*64 + lane
#define GWO_U4   100352   // gating out: hl*256 + ks*64 + lane
#define TOTAL_PK 100864   // uint4 count in ws (1.61 MB)

typedef short bf16x8 __attribute__((ext_vector_type(8)));
typedef float f32x16 __attribute__((ext_vector_type(16)));

__device__ __forceinline__ float tanh_fast(float x) {
    float e = __expf(2.0f * x);
    return fmaf(-2.0f, __builtin_amdgcn_rcpf(e + 1.0f), 1.0f);
}

// pack pair to bf16x2 word via RNE (compiler emits v_cvt_pk_bf16_f32)
__device__ __forceinline__ unsigned cvt_pk(float a, float b) {
    union { __hip_bfloat162 h; unsigned u; } c;
    c.h = __float22bfloat162_rn(make_float2(a, b));
    return c.u;
}
// split (a,b) -> hi word + lo word (2-term bf16 representation)
__device__ __forceinline__ void split_pair(float a, float b, unsigned& hw, unsigned& lw) {
    hw = cvt_pk(a, b);
    float ha = __uint_as_float(hw << 16);
    float hb = __uint_as_float(hw & 0xffff0000u);
    lw = cvt_pk(a - ha, b - hb);
}

__device__ __forceinline__ void lane32_swap(unsigned& d, unsigned& s) {
#if __has_builtin(__builtin_amdgcn_permlane32_swap)
    auto r = __builtin_amdgcn_permlane32_swap((int)d, (int)s, false, false);
    d = (unsigned)r[0];
    s = (unsigned)r[1];
#else
    unsigned pd = (unsigned)__shfl_xor((int)d, 32, 64);
    unsigned ps = (unsigned)__shfl_xor((int)s, 32, 64);
    bool up = (threadIdx.x & 32) != 0;
    unsigned nd = up ? ps : d;
    unsigned ns = up ? s : pd;
    d = nd; s = ns;
#endif
}

__device__ __forceinline__ bf16x8 mk8(unsigned a, unsigned b, unsigned c, unsigned d) {
    union { unsigned u[4]; bf16x8 v; } t;
    t.u[0] = a; t.u[1] = b; t.u[2] = c; t.u[3] = d;
    return t.v;
}
__device__ __forceinline__ bf16x8 ldA(const uint4* p) {
    union { uint4 q; bf16x8 v; } u; u.q = *p; return u.v;
}

// C-layout tv[16] (one jt) -> two B-frag slots (p=0,1) with hi/lo split + swap.
// Identical index algebra to round-3 (harness-validated).
__device__ __forceinline__ void epi_pack(const float (&tv)[16],
                                         bf16x8& Nh0, bf16x8& Nl0,
                                         bf16x8& Nh1, bf16x8& Nl1) {
#pragma unroll
    for (int p = 0; p < 2; ++p) {
        unsigned ah0, al0, ah1, al1, bh0, bl0, bh1, bl1;
        split_pair(tv[8 * p + 0], tv[8 * p + 1], ah0, al0);
        split_pair(tv[8 * p + 2], tv[8 * p + 3], ah1, al1);
        split_pair(tv[8 * p + 4], tv[8 * p + 5], bh0, bl0);
        split_pair(tv[8 * p + 6], tv[8 * p + 7], bh1, bl1);
        lane32_swap(ah0, bh0); lane32_swap(ah1, bh1);
        lane32_swap(al0, bl0); lane32_swap(al1, bl1);
        if (p == 0) { Nh0 = mk8(ah0, ah1, bh0, bh1); Nl0 = mk8(al0, al1, bl0, bl1); }
        else        { Nh1 = mk8(ah0, ah1, bh0, bh1); Nl1 = mk8(al0, al1, bl0, bl1); }
    }
}

// ---------------- prep: pack all weights into MFMA A-fragment order ----------------
__device__ __forceinline__ unsigned short rne_bf16(float v) {
    unsigned b = __float_as_uint(v);
    b += 0x7fffu + ((b >> 16) & 1u);
    return (unsigned short)(b >> 16);
}

__launch_bounds__(256)
__global__ void pack_wm_kernel(const float* __restrict__ ewm,
                               const float* __restrict__ gwm,
                               const float* __restrict__ gwo,
                               unsigned short* __restrict__ ws) {
    int t = blockIdx.x * 256 + threadIdx.x;
    unsigned short o[8];
    size_t dst;
    if (t < GMID_U4) {
        // experts: [el][jt(4)][ks(8)][lane]; j=jt*32+(lane&31), k=ks*16+(lane>>5)*8+u
        int lane = t & 63, ks = (t >> 6) & 7, jt = (t >> 9) & 3, el = t >> 11;
        int j  = jt * 32 + (lane & 31);
        int k0 = ks * 16 + (lane >> 5) * 8;
        const float* src = ewm + (size_t)el * 16384;
#pragma unroll
        for (int u = 0; u < 8; ++u) o[u] = rne_bf16(src[(k0 + u) * 128 + j]);
        dst = (size_t)el * 2048 + (size_t)((jt * 8 + ks) * 64 + lane);
    } else if (t < GWO_U4) {
        // gating mid: [l][hl][jt(2)][ks(4)][lane]; 64x64, hi/lo split
        int t2 = t - GMID_U4;
        int lane = t2 & 63, ks = (t2 >> 6) & 3, jt = (t2 >> 8) & 1,
            hl = (t2 >> 9) & 1, l = (t2 >> 10) & 1;
        int j  = jt * 32 + (lane & 31);
        int k0 = ks * 16 + (lane >> 5) * 8;
        const float* src = gwm + l * 4096;
#pragma unroll
        for (int u = 0; u < 8; ++u) {
            float v = src[(k0 + u) * 64 + j];
            unsigned short h = rne_bf16(v);
            if (hl == 0) o[u] = h;
            else {
                float r = v - __uint_as_float((unsigned)h << 16);
                o[u] = rne_bf16(r);
            }
        }
        dst = (size_t)GMID_U4 + (l * 2 + hl) * 512 + (jt * 4 + ks) * 64 + lane;
    } else if (t < TOTAL_PK) {
        // gating out: [hl][ks(4)][lane]; 64x16, j>=16 zero-padded
        int t3 = t - GWO_U4;
        int lane = t3 & 63, ks = (t3 >> 6) & 3, hl = t3 >> 8;
        int j  = lane & 31;
        int k0 = ks * 16 + (lane >> 5) * 8;
#pragma unroll
        for (int u = 0; u < 8; ++u) {
            float v = (j < 16) ? gwo[(k0 + u) * 16 + j] : 0.0f;
            unsigned short h = rne_bf16(v);
            if (hl == 0) o[u] = h;
            else {
                float r = v - __uint_as_float((unsigned)h << 16);
                o[u] = rne_bf16(r);
            }
        }
        dst = (size_t)GWO_U4 + hl * 256 + ks * 64 + lane;
    } else return;
    uint4 v;
    v.x = (unsigned)o[0] | ((unsigned)o[1] << 16);
    v.y = (unsigned)o[2] | ((unsigned)o[3] << 16);
    v.z = (unsigned)o[4] | ((unsigned)o[5] << 16);
    v.w = (unsigned)o[6] | ((unsigned)o[7] << 16);
    *((uint4*)ws + dst) = v;
}

// one expert mid layer (128x128): W A-frags from global (L2), h in regs
__device__ __forceinline__ void expert_mid(const uint4* __restrict__ A,
                                           const float* __restrict__ bias,
                                           int lane, int g2,
                                           bf16x8 (&Bh)[8], bf16x8 (&Bl)[8]) {
    bf16x8 Nh[8], Nl[8];
#pragma unroll
    for (int jt = 0; jt < 4; ++jt) {
        f32x16 acc;
#pragma unroll
        for (int qd = 0; qd < 4; ++qd) {
            const float4 bb = *(const float4*)(bias + jt * 32 + qd * 8 + g2 * 4);
            acc[4 * qd + 0] = bb.x; acc[4 * qd + 1] = bb.y;
            acc[4 * qd + 2] = bb.z; acc[4 * qd + 3] = bb.w;
        }
#pragma unroll
        for (int ks = 0; ks < 8; ++ks) {
            bf16x8 a = ldA(A + (jt * 8 + ks) * 64 + lane);
            acc = __builtin_amdgcn_mfma_f32_32x32x16_bf16(a, Bh[ks], acc, 0, 0, 0);
            acc = __builtin_amdgcn_mfma_f32_32x32x16_bf16(a, Bl[ks], acc, 0, 0, 0);
        }
        float tv[16];
#pragma unroll
        for (int r = 0; r < 16; ++r) tv[r] = tanh_fast(acc[r]);
        epi_pack(tv, Nh[2 * jt + 0], Nl[2 * jt + 0], Nh[2 * jt + 1], Nl[2 * jt + 1]);
    }
#pragma unroll
    for (int k = 0; k < 8; ++k) { Bh[k] = Nh[k]; Bl[k] = Nl[k]; }
}

__launch_bounds__(THREADS, 4)
__global__ void moe_fused(const float* __restrict__ x,
                          const float* __restrict__ ew1,
                          const float* __restrict__ eb1,
                          const float* __restrict__ ebm,
                          const float* __restrict__ ewo,
                          const float* __restrict__ ebo,
                          const float* __restrict__ gw1,
                          const float* __restrict__ gb1,
                          const float* __restrict__ gbm,
                          const float* __restrict__ gbo,
                          const uint4* __restrict__ wsA,
                          float* __restrict__ y) {
    __shared__ float gates_s[16 * 64];   // [e][tok]
    __shared__ float ybuf[64];           // cross-ehalf partials

    const int tid   = threadIdx.x;
    const int blk   = blockIdx.x;
    const int lane  = tid & 63;
    const int w_id  = tid >> 6;          // 0..3
    const int tile  = w_id >> 1;         // 0..1
    const int ehalf = w_id & 1;          // expert half
    const int t     = lane & 31;
    const int g2    = lane >> 5;
    const int wtok  = tile * 32 + t;     // 0..63
    const int gtok  = blk * T_BLK + wtok;
    const float ex0 = x[gtok * 2 + 0];
    const float ex1 = x[gtok * 2 + 1];

    // ================= gating (ehalf0 waves only, in-register MFMA) =================
    if (ehalf == 0) {
        bf16x8 Gh[4], Gl[4];
        // L1: 2 -> 64 directly in B-frag layout
#pragma unroll
        for (int ks = 0; ks < 4; ++ks) {
            int j8 = ks * 16 + g2 * 8;
            const float4 w00 = *(const float4*)(gw1 + j8);
            const float4 w01 = *(const float4*)(gw1 + j8 + 4);
            const float4 w10 = *(const float4*)(gw1 + 64 + j8);
            const float4 w11 = *(const float4*)(gw1 + 64 + j8 + 4);
            const float4 b0  = *(const float4*)(gb1 + j8);
            const float4 b1  = *(const float4*)(gb1 + j8 + 4);
            float t0 = tanh_fast(fmaf(ex0, w00.x, fmaf(ex1, w10.x, b0.x)));
            float t1 = tanh_fast(fmaf(ex0, w00.y, fmaf(ex1, w10.y, b0.y)));
            float t2 = tanh_fast(fmaf(ex0, w00.z, fmaf(ex1, w10.z, b0.z)));
            float t3 = tanh_fast(fmaf(ex0, w00.w, fmaf(ex1, w10.w, b0.w)));
            float t4 = tanh_fast(fmaf(ex0, w01.x, fmaf(ex1, w11.x, b1.x)));
            float t5 = tanh_fast(fmaf(ex0, w01.y, fmaf(ex1, w11.y, b1.y)));
            float t6 = tanh_fast(fmaf(ex0, w01.z, fmaf(ex1, w11.z, b1.z)));
            float t7 = tanh_fast(fmaf(ex0, w01.w, fmaf(ex1, w11.w, b1.w)));
            unsigned h0, l0, h1, l1, h2, l2, h3, l3;
            split_pair(t0, t1, h0, l0); split_pair(t2, t3, h1, l1);
            split_pair(t4, t5, h2, l2); split_pair(t6, t7, h3, l3);
            Gh[ks] = mk8(h0, h1, h2, h3);
            Gl[ks] = mk8(l0, l1, l2, l3);
        }
        // 2 mid layers (64x64), 3-term hi/lo MFMA
#pragma unroll
        for (int l = 0; l < 2; ++l) {
            bf16x8 NGh[4], NGl[4];
#pragma unroll
            for (int jt = 0; jt < 2; ++jt) {
                f32x16 acc;
#pragma unroll
                for (int qd = 0; qd < 4; ++qd) {
                    const float4 bb = *(const float4*)(gbm + l * 64 + jt * 32 + qd * 8 + g2 * 4);
                    acc[4 * qd + 0] = bb.x; acc[4 * qd + 1] = bb.y;
                    acc[4 * qd + 2] = bb.z; acc[4 * qd + 3] = bb.w;
                }
#pragma unroll
                for (int ks = 0; ks < 4; ++ks) {
                    bf16x8 ahi = ldA(wsA + GMID_U4 + (l * 2 + 0) * 512 + (jt * 4 + ks) * 64 + lane);
                    bf16x8 alo = ldA(wsA + GMID_U4 + (l * 2 + 1) * 512 + (jt * 4 + ks) * 64 + lane);
                    acc = __builtin_amdgcn_mfma_f32_32x32x16_bf16(ahi, Gh[ks], acc, 0, 0, 0);
                    acc = __builtin_amdgcn_mfma_f32_32x32x16_bf16(ahi, Gl[ks], acc, 0, 0, 0);
                    acc = __builtin_amdgcn_mfma_f32_32x32x16_bf16(alo, Gh[ks], acc, 0, 0, 0);
                }
                float tv[16];
#pragma unroll
                for (int r = 0; r < 16; ++r) tv[r] = tanh_fast(acc[r]);
                epi_pack(tv, NGh[2 * jt + 0], NGl[2 * jt + 0], NGh[2 * jt + 1], NGl[2 * jt + 1]);
            }
#pragma unroll
            for (int k = 0; k < 4; ++k) { Gh[k] = NGh[k]; Gl[k] = NGl[k]; }
        }
        // logits (64 -> 16) + sin -> gates LDS
        {
            f32x16 acc;
            const float4 ba = *(const float4*)(gbo + g2 * 4);
            const float4 bc = *(const float4*)(gbo + 8 + g2 * 4);
            acc[0] = ba.x; acc[1] = ba.y; acc[2] = ba.z; acc[3] = ba.w;
            acc[4] = bc.x; acc[5] = bc.y; acc[6] = bc.z; acc[7] = bc.w;
#pragma unroll
            for (int r = 8; r < 16; ++r) acc[r] = 0.0f;
#pragma unroll
            for (int ks = 0; ks < 4; ++ks) {
                bf16x8 ahi = ldA(wsA + GWO_U4 + 0 * 256 + ks * 64 + lane);
                bf16x8 alo = ldA(wsA + GWO_U4 + 1 * 256 + ks * 64 + lane);
                acc = __builtin_amdgcn_mfma_f32_32x32x16_bf16(ahi, Gh[ks], acc, 0, 0, 0);
                acc = __builtin_amdgcn_mfma_f32_32x32x16_bf16(ahi, Gl[ks], acc, 0, 0, 0);
                acc = __builtin_amdgcn_mfma_f32_32x32x16_bf16(alo, Gh[ks], acc, 0, 0, 0);
            }
            const float FIVE_PI = 15.707963267948966f;
#pragma unroll
            for (int r = 0; r < 8; ++r) {
                int e_own = (r & 3) + 8 * (r >> 2) + 4 * g2;   // row index = expert
                gates_s[e_own * 64 + wtok] = __sinf(FIVE_PI * acc[r]);
            }
        }
    }
    __syncthreads();   // gates visible to all waves

    // ================= experts (8 per wave, register-resident h) =================
    float yacc = 0.0f;
    bf16x8 Bh[8], Bl[8];
    const int e_begin = ehalf * 8;

#pragma unroll 1
    for (int le = 0; le < 8; ++le) {
        const int e = e_begin + le;
        // ---- EL1: 2 -> 128, direct B-frag ----
        {
            const float* w1 = ew1 + e * 256;
            const float* b1 = eb1 + e * 128;
#pragma unroll
            for (int ks = 0; ks < 8; ++ks) {
                int j8 = ks * 16 + g2 * 8;
                const float4 wa0 = *(const float4*)(w1 + j8);
                const float4 wa1 = *(const float4*)(w1 + j8 + 4);
                const float4 wb0 = *(const float4*)(w1 + 128 + j8);
                const float4 wb1 = *(const float4*)(w1 + 128 + j8 + 4);
                const float4 bb0 = *(const float4*)(b1 + j8);
                const float4 bb1 = *(const float4*)(b1 + j8 + 4);
                float t0 = tanh_fast(fmaf(ex0, wa0.x, fmaf(ex1, wb0.x, bb0.x)));
                float t1 = tanh_fast(fmaf(ex0, wa0.y, fmaf(ex1, wb0.y, bb0.y)));
                float t2 = tanh_fast(fmaf(ex0, wa0.z, fmaf(ex1, wb0.z, bb0.z)));
                float t3 = tanh_fast(fmaf(ex0, wa0.w, fmaf(ex1, wb0.w, bb0.w)));
                float t4 = tanh_fast(fmaf(ex0, wa1.x, fmaf(ex1, wb1.x, bb1.x)));
                float t5 = tanh_fast(fmaf(ex0, wa1.y, fmaf(ex1, wb1.y, bb1.y)));
                float t6 = tanh_fast(fmaf(ex0, wa1.z, fmaf(ex1, wb1.z, bb1.z)));
                float t7 = tanh_fast(fmaf(ex0, wa1.w, fmaf(ex1, wb1.w, bb1.w)));
                unsigned h0, l0, h1, l1, h2, l2, h3, l3;
                split_pair(t0, t1, h0, l0); split_pair(t2, t3, h1, l1);
                split_pair(t4, t5, h2, l2); split_pair(t6, t7, h3, l3);
                Bh[ks] = mk8(h0, h1, h2, h3);
                Bl[ks] = mk8(l0, l1, l2, l3);
            }
        }
        // ---- 3 mid layers ----
        const uint4* A = wsA + (size_t)(e * 3) * 2048;
        expert_mid(A,        ebm + (e * 3 + 0) * 128, lane, g2, Bh, Bl);
        expert_mid(A + 2048, ebm + (e * 3 + 1) * 128, lane, g2, Bh, Bl);
        expert_mid(A + 4096, ebm + (e * 3 + 2) * 128, lane, g2, Bh, Bl);
        // ---- output dot + gate ----
        {
            float ps = 0.0f;
            const float* wo = ewo + e * 128;
#pragma unroll
            for (int ks = 0; ks < 8; ++ks) {
                int j8 = ks * 16 + g2 * 8;
                const float4 w0 = *(const float4*)(wo + j8);
                const float4 w1v = *(const float4*)(wo + j8 + 4);
                union { bf16x8 v; unsigned u[4]; } H, L;
                H.v = Bh[ks]; L.v = Bl[ks];
                float e0 = __uint_as_float(H.u[0] << 16) + __uint_as_float(L.u[0] << 16);
                float e1 = __uint_as_float(H.u[0] & 0xffff0000u) + __uint_as_float(L.u[0] & 0xffff0000u);
                float e2 = __uint_as_float(H.u[1] << 16) + __uint_as_float(L.u[1] << 16);
                float e3 = __uint_as_float(H.u[1] & 0xffff0000u) + __uint_as_float(L.u[1] & 0xffff0000u);
                float e4 = __uint_as_float(H.u[2] << 16) + __uint_as_float(L.u[2] << 16);
                float e5 = __uint_as_float(H.u[2] & 0xffff0000u) + __uint_as_float(L.u[2] & 0xffff0000u);
                float e6 = __uint_as_float(H.u[3] << 16) + __uint_as_float(L.u[3] << 16);
                float e7 = __uint_as_float(H.u[3] & 0xffff0000u) + __uint_as_float(L.u[3] & 0xffff0000u);
                ps = fmaf(e0, w0.x, ps);  ps = fmaf(e1, w0.y, ps);
                ps = fmaf(e2, w0.z, ps);  ps = fmaf(e3, w0.w, ps);
                ps = fmaf(e4, w1v.x, ps); ps = fmaf(e5, w1v.y, ps);
                ps = fmaf(e6, w1v.z, ps); ps = fmaf(e7, w1v.w, ps);
            }
            ps += __shfl_xor(ps, 32, 64);
            float eo = ps + ebo[e];
            yacc = fmaf(gates_s[e * 64 + wtok], eo, yacc);
        }
    }

    // ================= combine expert halves =================
    if (ehalf == 1 && lane < 32) ybuf[wtok] = yacc;
    __syncthreads();
    if (ehalf == 0 && lane < 32) y[gtok] = yacc + ybuf[wtok];
}

extern "C" void kernel_launch(void* const* d_in, const int* in_sizes, int n_in,
                              void* d_out, int out_size, void* d_ws, size_t ws_size,
                              hipStream_t stream) {
    const float* x   = (const float*)d_in[0];
    const float* ew1 = (const float*)d_in[1];
    const float* eb1 = (const float*)d_in[2];
    const float* ewm = (const float*)d_in[3];
    const float* ebm = (const float*)d_in[4];
    const float* ewo = (const float*)d_in[5];
    const float* ebo = (const float*)d_in[6];
    const float* gw1 = (const float*)d_in[7];
    const float* gb1 = (const float*)d_in[8];
    const float* gwm = (const float*)d_in[9];
    const float* gbm = (const float*)d_in[10];
    const float* gwo = (const float*)d_in[11];
    const float* gbo = (const float*)d_in[12];
    float* y = (float*)d_out;
    unsigned short* ws = (unsigned short*)d_ws;   // 1.61 MB packed A-frags

    pack_wm_kernel<<<TOTAL_PK / 256, 256, 0, stream>>>(ewm, gwm, gwo, ws);

    moe_fused<<<dim3(N_TOK / T_BLK), dim3(THREADS), 0, stream>>>(
        x, ew1, eb1, ebm, ewo, ebo, gw1, gb1, gbm, gbo,
        (const uint4*)ws, y);
}

// Round 6
// 384.005 us; speedup vs baseline: 1.9429x; 1.2411x over previous
//
#include <hip/hip_runtime.h>
#include <hip/hip_bf16.h>
#include <math.h>

// Fused MoE, round 5 (resubmit — R5 bench was an infra timeout, no data):
// single-term bf16 h in expert path (no spill @ 4 waves/SIMD).
//  - 1024 blocks x 256 thr (4 waves). Wave = (tile = w_id>>1, ehalf = w_id&1).
//  - Each wave: 32 tokens, 8 experts, h in registers as 32x32x16 MFMA
//    B-fragments (single RNE bf16; W also single RNE bf16 — both quantizations
//    proven invisible: R1 fp32 and R2-4 W-bf16 give identical absmax).
//  - Gating keeps 3-term hi/lo MFMA (5*pi amplification), ehalf0 waves only.
//  - W A-frags global->reg (L2-resident, prepacked into d_ws).

#define N_TOK 65536
#define T_BLK 64
#define THREADS 256

#define EXP_U4   0        // experts: 48 layers * 2048 uint4 (32KB each)
#define GMID_U4  98304    // gating mid: (l*2+hl)*512 + (jt*4+ks)*64 + lane
#define GWO_U4   100352   // gating out: hl*256 + ks*64 + lane
#define TOTAL_PK 100864   // uint4 count in ws (1.61 MB)

typedef short bf16x8 __attribute__((ext_vector_type(8)));
typedef float f32x16 __attribute__((ext_vector_type(16)));

__device__ __forceinline__ float tanh_fast(float x) {
    float e = __expf(2.0f * x);
    return fmaf(-2.0f, __builtin_amdgcn_rcpf(e + 1.0f), 1.0f);
}

// pack pair to bf16x2 word via RNE (compiler emits v_cvt_pk_bf16_f32)
__device__ __forceinline__ unsigned cvt_pk(float a, float b) {
    union { __hip_bfloat162 h; unsigned u; } c;
    c.h = __float22bfloat162_rn(make_float2(a, b));
    return c.u;
}
// split (a,b) -> hi word + lo word (2-term bf16, gating only)
__device__ __forceinline__ void split_pair(float a, float b, unsigned& hw, unsigned& lw) {
    hw = cvt_pk(a, b);
    float ha = __uint_as_float(hw << 16);
    float hb = __uint_as_float(hw & 0xffff0000u);
    lw = cvt_pk(a - ha, b - hb);
}

__device__ __forceinline__ void lane32_swap(unsigned& d, unsigned& s) {
#if __has_builtin(__builtin_amdgcn_permlane32_swap)
    auto r = __builtin_amdgcn_permlane32_swap((int)d, (int)s, false, false);
    d = (unsigned)r[0];
    s = (unsigned)r[1];
#else
    unsigned pd = (unsigned)__shfl_xor((int)d, 32, 64);
    unsigned ps = (unsigned)__shfl_xor((int)s, 32, 64);
    bool up = (threadIdx.x & 32) != 0;
    unsigned nd = up ? ps : d;
    unsigned ns = up ? s : pd;
    d = nd; s = ns;
#endif
}

__device__ __forceinline__ bf16x8 mk8(unsigned a, unsigned b, unsigned c, unsigned d) {
    union { unsigned u[4]; bf16x8 v; } t;
    t.u[0] = a; t.u[1] = b; t.u[2] = c; t.u[3] = d;
    return t.v;
}
__device__ __forceinline__ bf16x8 ldA(const uint4* p) {
    union { uint4 q; bf16x8 v; } u; u.q = *p; return u.v;
}

// ---------------- prep: pack all weights into MFMA A-fragment order ----------------
__device__ __forceinline__ unsigned short rne_bf16(float v) {
    unsigned b = __float_as_uint(v);
    b += 0x7fffu + ((b >> 16) & 1u);
    return (unsigned short)(b >> 16);
}

__launch_bounds__(256)
__global__ void pack_wm_kernel(const float* __restrict__ ewm,
                               const float* __restrict__ gwm,
                               const float* __restrict__ gwo,
                               unsigned short* __restrict__ ws) {
    int t = blockIdx.x * 256 + threadIdx.x;
    unsigned short o[8];
    size_t dst;
    if (t < GMID_U4) {
        // experts: [el][jt(4)][ks(8)][lane]; j=jt*32+(lane&31), k=ks*16+(lane>>5)*8+u
        int lane = t & 63, ks = (t >> 6) & 7, jt = (t >> 9) & 3, el = t >> 11;
        int j  = jt * 32 + (lane & 31);
        int k0 = ks * 16 + (lane >> 5) * 8;
        const float* src = ewm + (size_t)el * 16384;
#pragma unroll
        for (int u = 0; u < 8; ++u) o[u] = rne_bf16(src[(k0 + u) * 128 + j]);
        dst = (size_t)el * 2048 + (size_t)((jt * 8 + ks) * 64 + lane);
    } else if (t < GWO_U4) {
        // gating mid: [l][hl][jt(2)][ks(4)][lane]; 64x64, hi/lo split
        int t2 = t - GMID_U4;
        int lane = t2 & 63, ks = (t2 >> 6) & 3, jt = (t2 >> 8) & 1,
            hl = (t2 >> 9) & 1, l = (t2 >> 10) & 1;
        int j  = jt * 32 + (lane & 31);
        int k0 = ks * 16 + (lane >> 5) * 8;
        const float* src = gwm + l * 4096;
#pragma unroll
        for (int u = 0; u < 8; ++u) {
            float v = src[(k0 + u) * 64 + j];
            unsigned short h = rne_bf16(v);
            if (hl == 0) o[u] = h;
            else {
                float r = v - __uint_as_float((unsigned)h << 16);
                o[u] = rne_bf16(r);
            }
        }
        dst = (size_t)GMID_U4 + (l * 2 + hl) * 512 + (jt * 4 + ks) * 64 + lane;
    } else if (t < TOTAL_PK) {
        // gating out: [hl][ks(4)][lane]; 64x16, j>=16 zero-padded
        int t3 = t - GWO_U4;
        int lane = t3 & 63, ks = (t3 >> 6) & 3, hl = t3 >> 8;
        int j  = lane & 31;
        int k0 = ks * 16 + (lane >> 5) * 8;
#pragma unroll
        for (int u = 0; u < 8; ++u) {
            float v = (j < 16) ? gwo[(k0 + u) * 16 + j] : 0.0f;
            unsigned short h = rne_bf16(v);
            if (hl == 0) o[u] = h;
            else {
                float r = v - __uint_as_float((unsigned)h << 16);
                o[u] = rne_bf16(r);
            }
        }
        dst = (size_t)GWO_U4 + hl * 256 + ks * 64 + lane;
    } else return;
    uint4 v;
    v.x = (unsigned)o[0] | ((unsigned)o[1] << 16);
    v.y = (unsigned)o[2] | ((unsigned)o[3] << 16);
    v.z = (unsigned)o[4] | ((unsigned)o[5] << 16);
    v.w = (unsigned)o[6] | ((unsigned)o[7] << 16);
    *((uint4*)ws + dst) = v;
}

// one expert mid layer (128x128): W A-frags from global (L2), single-term h
__device__ __forceinline__ void expert_mid(const uint4* __restrict__ A,
                                           const float* __restrict__ bias,
                                           int lane, int g2,
                                           bf16x8 (&B)[8]) {
    bf16x8 N[8];
#pragma unroll
    for (int jt = 0; jt < 4; ++jt) {
        f32x16 acc;
#pragma unroll
        for (int qd = 0; qd < 4; ++qd) {
            const float4 bb = *(const float4*)(bias + jt * 32 + qd * 8 + g2 * 4);
            acc[4 * qd + 0] = bb.x; acc[4 * qd + 1] = bb.y;
            acc[4 * qd + 2] = bb.z; acc[4 * qd + 3] = bb.w;
        }
#pragma unroll
        for (int ks = 0; ks < 8; ++ks) {
            bf16x8 a = ldA(A + (jt * 8 + ks) * 64 + lane);
            acc = __builtin_amdgcn_mfma_f32_32x32x16_bf16(a, B[ks], acc, 0, 0, 0);
        }
#pragma unroll
        for (int p = 0; p < 2; ++p) {
            float t0 = tanh_fast(acc[8 * p + 0]), t1 = tanh_fast(acc[8 * p + 1]);
            float t2 = tanh_fast(acc[8 * p + 2]), t3 = tanh_fast(acc[8 * p + 3]);
            float t4 = tanh_fast(acc[8 * p + 4]), t5 = tanh_fast(acc[8 * p + 5]);
            float t6 = tanh_fast(acc[8 * p + 6]), t7 = tanh_fast(acc[8 * p + 7]);
            unsigned ah0 = cvt_pk(t0, t1), ah1 = cvt_pk(t2, t3);
            unsigned bh0 = cvt_pk(t4, t5), bh1 = cvt_pk(t6, t7);
            lane32_swap(ah0, bh0); lane32_swap(ah1, bh1);
            N[2 * jt + p] = mk8(ah0, ah1, bh0, bh1);
        }
    }
#pragma unroll
    for (int k = 0; k < 8; ++k) B[k] = N[k];
}

__launch_bounds__(THREADS, 4)
__global__ void moe_fused(const float* __restrict__ x,
                          const float* __restrict__ ew1,
                          const float* __restrict__ eb1,
                          const float* __restrict__ ebm,
                          const float* __restrict__ ewo,
                          const float* __restrict__ ebo,
                          const float* __restrict__ gw1,
                          const float* __restrict__ gb1,
                          const float* __restrict__ gbm,
                          const float* __restrict__ gbo,
                          const uint4* __restrict__ wsA,
                          float* __restrict__ y) {
    __shared__ float gates_s[16 * 64];   // [e][tok]
    __shared__ float ybuf[64];           // cross-ehalf partials

    const int tid   = threadIdx.x;
    const int blk   = blockIdx.x;
    const int lane  = tid & 63;
    const int w_id  = tid >> 6;          // 0..3
    const int tile  = w_id >> 1;         // 0..1
    const int ehalf = w_id & 1;          // expert half
    const int t     = lane & 31;
    const int g2    = lane >> 5;
    const int wtok  = tile * 32 + t;     // 0..63
    const int gtok  = blk * T_BLK + wtok;
    const float ex0 = x[gtok * 2 + 0];
    const float ex1 = x[gtok * 2 + 1];

    // ================= gating (ehalf0 waves only, 3-term hi/lo MFMA) =================
    if (ehalf == 0) {
        bf16x8 Gh[4], Gl[4];
        // L1: 2 -> 64 directly in B-frag layout
#pragma unroll
        for (int ks = 0; ks < 4; ++ks) {
            int j8 = ks * 16 + g2 * 8;
            const float4 w00 = *(const float4*)(gw1 + j8);
            const float4 w01 = *(const float4*)(gw1 + j8 + 4);
            const float4 w10 = *(const float4*)(gw1 + 64 + j8);
            const float4 w11 = *(const float4*)(gw1 + 64 + j8 + 4);
            const float4 b0  = *(const float4*)(gb1 + j8);
            const float4 b1  = *(const float4*)(gb1 + j8 + 4);
            float t0 = tanh_fast(fmaf(ex0, w00.x, fmaf(ex1, w10.x, b0.x)));
            float t1 = tanh_fast(fmaf(ex0, w00.y, fmaf(ex1, w10.y, b0.y)));
            float t2 = tanh_fast(fmaf(ex0, w00.z, fmaf(ex1, w10.z, b0.z)));
            float t3 = tanh_fast(fmaf(ex0, w00.w, fmaf(ex1, w10.w, b0.w)));
            float t4 = tanh_fast(fmaf(ex0, w01.x, fmaf(ex1, w11.x, b1.x)));
            float t5 = tanh_fast(fmaf(ex0, w01.y, fmaf(ex1, w11.y, b1.y)));
            float t6 = tanh_fast(fmaf(ex0, w01.z, fmaf(ex1, w11.z, b1.z)));
            float t7 = tanh_fast(fmaf(ex0, w01.w, fmaf(ex1, w11.w, b1.w)));
            unsigned h0, l0, h1, l1, h2, l2, h3, l3;
            split_pair(t0, t1, h0, l0); split_pair(t2, t3, h1, l1);
            split_pair(t4, t5, h2, l2); split_pair(t6, t7, h3, l3);
            Gh[ks] = mk8(h0, h1, h2, h3);
            Gl[ks] = mk8(l0, l1, l2, l3);
        }
        // 2 mid layers (64x64), 3-term hi/lo MFMA
#pragma unroll
        for (int l = 0; l < 2; ++l) {
            bf16x8 NGh[4], NGl[4];
#pragma unroll
            for (int jt = 0; jt < 2; ++jt) {
                f32x16 acc;
#pragma unroll
                for (int qd = 0; qd < 4; ++qd) {
                    const float4 bb = *(const float4*)(gbm + l * 64 + jt * 32 + qd * 8 + g2 * 4);
                    acc[4 * qd + 0] = bb.x; acc[4 * qd + 1] = bb.y;
                    acc[4 * qd + 2] = bb.z; acc[4 * qd + 3] = bb.w;
                }
#pragma unroll
                for (int ks = 0; ks < 4; ++ks) {
                    bf16x8 ahi = ldA(wsA + GMID_U4 + (l * 2 + 0) * 512 + (jt * 4 + ks) * 64 + lane);
                    bf16x8 alo = ldA(wsA + GMID_U4 + (l * 2 + 1) * 512 + (jt * 4 + ks) * 64 + lane);
                    acc = __builtin_amdgcn_mfma_f32_32x32x16_bf16(ahi, Gh[ks], acc, 0, 0, 0);
                    acc = __builtin_amdgcn_mfma_f32_32x32x16_bf16(ahi, Gl[ks], acc, 0, 0, 0);
                    acc = __builtin_amdgcn_mfma_f32_32x32x16_bf16(alo, Gh[ks], acc, 0, 0, 0);
                }
                float tv[16];
#pragma unroll
                for (int r = 0; r < 16; ++r) tv[r] = tanh_fast(acc[r]);
#pragma unroll
                for (int p = 0; p < 2; ++p) {
                    unsigned ah0, al0, ah1, al1, bh0, bl0, bh1, bl1;
                    split_pair(tv[8 * p + 0], tv[8 * p + 1], ah0, al0);
                    split_pair(tv[8 * p + 2], tv[8 * p + 3], ah1, al1);
                    split_pair(tv[8 * p + 4], tv[8 * p + 5], bh0, bl0);
                    split_pair(tv[8 * p + 6], tv[8 * p + 7], bh1, bl1);
                    lane32_swap(ah0, bh0); lane32_swap(ah1, bh1);
                    lane32_swap(al0, bl0); lane32_swap(al1, bl1);
                    NGh[2 * jt + p] = mk8(ah0, ah1, bh0, bh1);
                    NGl[2 * jt + p] = mk8(al0, al1, bl0, bl1);
                }
            }
#pragma unroll
            for (int k = 0; k < 4; ++k) { Gh[k] = NGh[k]; Gl[k] = NGl[k]; }
        }
        // logits (64 -> 16) + sin -> gates LDS
        {
            f32x16 acc;
            const float4 ba = *(const float4*)(gbo + g2 * 4);
            const float4 bc = *(const float4*)(gbo + 8 + g2 * 4);
            acc[0] = ba.x; acc[1] = ba.y; acc[2] = ba.z; acc[3] = ba.w;
            acc[4] = bc.x; acc[5] = bc.y; acc[6] = bc.z; acc[7] = bc.w;
#pragma unroll
            for (int r = 8; r < 16; ++r) acc[r] = 0.0f;
#pragma unroll
            for (int ks = 0; ks < 4; ++ks) {
                bf16x8 ahi = ldA(wsA + GWO_U4 + 0 * 256 + ks * 64 + lane);
                bf16x8 alo = ldA(wsA + GWO_U4 + 1 * 256 + ks * 64 + lane);
                acc = __builtin_amdgcn_mfma_f32_32x32x16_bf16(ahi, Gh[ks], acc, 0, 0, 0);
                acc = __builtin_amdgcn_mfma_f32_32x32x16_bf16(ahi, Gl[ks], acc, 0, 0, 0);
                acc = __builtin_amdgcn_mfma_f32_32x32x16_bf16(alo, Gh[ks], acc, 0, 0, 0);
            }
            const float FIVE_PI = 15.707963267948966f;
#pragma unroll
            for (int r = 0; r < 8; ++r) {
                int e_own = (r & 3) + 8 * (r >> 2) + 4 * g2;   // row index = expert
                gates_s[e_own * 64 + wtok] = __sinf(FIVE_PI * acc[r]);
            }
        }
    }
    __syncthreads();   // gates visible to all waves

    // ================= experts (8 per wave, single-term register h) =================
    float yacc = 0.0f;
    bf16x8 B[8];
    const int e_begin = ehalf * 8;

#pragma unroll 1
    for (int le = 0; le < 8; ++le) {
        const int e = e_begin + le;
        // ---- EL1: 2 -> 128, direct B-frag ----
        {
            const float* w1 = ew1 + e * 256;
            const float* b1 = eb1 + e * 128;
#pragma unroll
            for (int ks = 0; ks < 8; ++ks) {
                int j8 = ks * 16 + g2 * 8;
                const float4 wa0 = *(const float4*)(w1 + j8);
                const float4 wa1 = *(const float4*)(w1 + j8 + 4);
                const float4 wb0 = *(const float4*)(w1 + 128 + j8);
                const float4 wb1 = *(const float4*)(w1 + 128 + j8 + 4);
                const float4 bb0 = *(const float4*)(b1 + j8);
                const float4 bb1 = *(const float4*)(b1 + j8 + 4);
                float t0 = tanh_fast(fmaf(ex0, wa0.x, fmaf(ex1, wb0.x, bb0.x)));
                float t1 = tanh_fast(fmaf(ex0, wa0.y, fmaf(ex1, wb0.y, bb0.y)));
                float t2 = tanh_fast(fmaf(ex0, wa0.z, fmaf(ex1, wb0.z, bb0.z)));
                float t3 = tanh_fast(fmaf(ex0, wa0.w, fmaf(ex1, wb0.w, bb0.w)));
                float t4 = tanh_fast(fmaf(ex0, wa1.x, fmaf(ex1, wb1.x, bb1.x)));
                float t5 = tanh_fast(fmaf(ex0, wa1.y, fmaf(ex1, wb1.y, bb1.y)));
                float t6 = tanh_fast(fmaf(ex0, wa1.z, fmaf(ex1, wb1.z, bb1.z)));
                float t7 = tanh_fast(fmaf(ex0, wa1.w, fmaf(ex1, wb1.w, bb1.w)));
                B[ks] = mk8(cvt_pk(t0, t1), cvt_pk(t2, t3),
                            cvt_pk(t4, t5), cvt_pk(t6, t7));
            }
        }
        // ---- 3 mid layers ----
        const uint4* A = wsA + (size_t)(e * 3) * 2048;
        expert_mid(A,        ebm + (e * 3 + 0) * 128, lane, g2, B);
        expert_mid(A + 2048, ebm + (e * 3 + 1) * 128, lane, g2, B);
        expert_mid(A + 4096, ebm + (e * 3 + 2) * 128, lane, g2, B);
        // ---- output dot + gate ----
        {
            float ps = 0.0f;
            const float* wo = ewo + e * 128;
#pragma unroll
            for (int ks = 0; ks < 8; ++ks) {
                int j8 = ks * 16 + g2 * 8;
                const float4 w0 = *(const float4*)(wo + j8);
                const float4 w1v = *(const float4*)(wo + j8 + 4);
                union { bf16x8 v; unsigned u[4]; } H;
                H.v = B[ks];
                float e0 = __uint_as_float(H.u[0] << 16);
                float e1 = __uint_as_float(H.u[0] & 0xffff0000u);
                float e2 = __uint_as_float(H.u[1] << 16);
                float e3 = __uint_as_float(H.u[1] & 0xffff0000u);
                float e4 = __uint_as_float(H.u[2] << 16);
                float e5 = __uint_as_float(H.u[2] & 0xffff0000u);
                float e6 = __uint_as_float(H.u[3] << 16);
                float e7 = __uint_as_float(H.u[3] & 0xffff0000u);
                ps = fmaf(e0, w0.x, ps);  ps = fmaf(e1, w0.y, ps);
                ps = fmaf(e2, w0.z, ps);  ps = fmaf(e3, w0.w, ps);
                ps = fmaf(e4, w1v.x, ps); ps = fmaf(e5, w1v.y, ps);
                ps = fmaf(e6, w1v.z, ps); ps = fmaf(e7, w1v.w, ps);
            }
            ps += __shfl_xor(ps, 32, 64);
            float eo = ps + ebo[e];
            yacc = fmaf(gates_s[e * 64 + wtok], eo, yacc);
        }
    }

    // ================= combine expert halves =================
    if (ehalf == 1 && lane < 32) ybuf[wtok] = yacc;
    __syncthreads();
    if (ehalf == 0 && lane < 32) y[gtok] = yacc + ybuf[wtok];
}

extern "C" void kernel_launch(void* const* d_in, const int* in_sizes, int n_in,
                              void* d_out, int out_size, void* d_ws, size_t ws_size,
                              hipStream_t stream) {
    const float* x   = (const float*)d_in[0];
    const float* ew1 = (const float*)d_in[1];
    const float* eb1 = (const float*)d_in[2];
    const float* ewm = (const float*)d_in[3];
    const float* ebm = (const float*)d_in[4];
    const float* ewo = (const float*)d_in[5];
    const float* ebo = (const float*)d_in[6];
    const float* gw1 = (const float*)d_in[7];
    const float* gb1 = (const float*)d_in[8];
    const float* gbm = (const float*)d_in[10];
    const float* gwm = (const float*)d_in[9];
    const float* gwo = (const float*)d_in[11];
    const float* gbo = (const float*)d_in[12];
    float* y = (float*)d_out;
    unsigned short* ws = (unsigned short*)d_ws;   // 1.61 MB packed A-frags

    pack_wm_kernel<<<TOTAL_PK / 256, 256, 0, stream>>>(ewm, gwm, gwo, ws);

    moe_fused<<<dim3(N_TOK / T_BLK), dim3(THREADS), 0, stream>>>(
        x, ew1, eb1, ebm, ewo, ebo, gw1, gb1, gbm, gbo,
        (const uint4*)ws, y);
}

// Round 7
// 342.895 us; speedup vs baseline: 2.1758x; 1.1199x over previous
//
#include <hip/hip_runtime.h>
#include <hip/hip_bf16.h>
#include <math.h>

// Fused MoE, round 7: 4-way expert split for occupancy (grid was the limiter).
//  - 2048 blocks x 256 thr (4 waves). Block = 32 tokens; wave w owns experts
//    w*4..w*4+3. h in registers as 32x32x16 MFMA B-fragments (single RNE bf16).
//  - Deferred gating: wave0 computes gates (3-term hi/lo MFMA) while waves 1-3
//    run their experts; every wave stores pre-gate eo into LDS; ONE barrier;
//    wave0 applies gates and writes y. No other synchronization.
//  - W A-frags global->reg (L2-resident, prepacked into d_ws). Same inner
//    loops, layouts, and tanh as round 6 (clean A/B on occupancy).

#define N_TOK 65536
#define T_BLK 32
#define THREADS 256

#define EXP_U4   0        // experts: 48 layers * 2048 uint4 (32KB each)
#define GMID_U4  98304    // gating mid: (l*2+hl)*512 + (jt*4+ks)*64 + lane
#define GWO_U4   100352   // gating out: hl*256 + ks*64 + lane
#define TOTAL_PK 100864   // uint4 count in ws (1.61 MB)

typedef short bf16x8 __attribute__((ext_vector_type(8)));
typedef float f32x16 __attribute__((ext_vector_type(16)));

__device__ __forceinline__ float tanh_fast(float x) {
    float e = __expf(2.0f * x);
    return fmaf(-2.0f, __builtin_amdgcn_rcpf(e + 1.0f), 1.0f);
}

// pack pair to bf16x2 word via RNE (compiler emits v_cvt_pk_bf16_f32)
__device__ __forceinline__ unsigned cvt_pk(float a, float b) {
    union { __hip_bfloat162 h; unsigned u; } c;
    c.h = __float22bfloat162_rn(make_float2(a, b));
    return c.u;
}
// split (a,b) -> hi word + lo word (2-term bf16, gating only)
__device__ __forceinline__ void split_pair(float a, float b, unsigned& hw, unsigned& lw) {
    hw = cvt_pk(a, b);
    float ha = __uint_as_float(hw << 16);
    float hb = __uint_as_float(hw & 0xffff0000u);
    lw = cvt_pk(a - ha, b - hb);
}

__device__ __forceinline__ void lane32_swap(unsigned& d, unsigned& s) {
#if __has_builtin(__builtin_amdgcn_permlane32_swap)
    auto r = __builtin_amdgcn_permlane32_swap((int)d, (int)s, false, false);
    d = (unsigned)r[0];
    s = (unsigned)r[1];
#else
    unsigned pd = (unsigned)__shfl_xor((int)d, 32, 64);
    unsigned ps = (unsigned)__shfl_xor((int)s, 32, 64);
    bool up = (threadIdx.x & 32) != 0;
    unsigned nd = up ? ps : d;
    unsigned ns = up ? s : pd;
    d = nd; s = ns;
#endif
}

__device__ __forceinline__ bf16x8 mk8(unsigned a, unsigned b, unsigned c, unsigned d) {
    union { unsigned u[4]; bf16x8 v; } t;
    t.u[0] = a; t.u[1] = b; t.u[2] = c; t.u[3] = d;
    return t.v;
}
__device__ __forceinline__ bf16x8 ldA(const uint4* p) {
    union { uint4 q; bf16x8 v; } u; u.q = *p; return u.v;
}

// ---------------- prep: pack all weights into MFMA A-fragment order ----------------
__device__ __forceinline__ unsigned short rne_bf16(float v) {
    unsigned b = __float_as_uint(v);
    b += 0x7fffu + ((b >> 16) & 1u);
    return (unsigned short)(b >> 16);
}

__launch_bounds__(256)
__global__ void pack_wm_kernel(const float* __restrict__ ewm,
                               const float* __restrict__ gwm,
                               const float* __restrict__ gwo,
                               unsigned short* __restrict__ ws) {
    int t = blockIdx.x * 256 + threadIdx.x;
    unsigned short o[8];
    size_t dst;
    if (t < GMID_U4) {
        // experts: [el][jt(4)][ks(8)][lane]; j=jt*32+(lane&31), k=ks*16+(lane>>5)*8+u
        int lane = t & 63, ks = (t >> 6) & 7, jt = (t >> 9) & 3, el = t >> 11;
        int j  = jt * 32 + (lane & 31);
        int k0 = ks * 16 + (lane >> 5) * 8;
        const float* src = ewm + (size_t)el * 16384;
#pragma unroll
        for (int u = 0; u < 8; ++u) o[u] = rne_bf16(src[(k0 + u) * 128 + j]);
        dst = (size_t)el * 2048 + (size_t)((jt * 8 + ks) * 64 + lane);
    } else if (t < GWO_U4) {
        // gating mid: [l][hl][jt(2)][ks(4)][lane]; 64x64, hi/lo split
        int t2 = t - GMID_U4;
        int lane = t2 & 63, ks = (t2 >> 6) & 3, jt = (t2 >> 8) & 1,
            hl = (t2 >> 9) & 1, l = (t2 >> 10) & 1;
        int j  = jt * 32 + (lane & 31);
        int k0 = ks * 16 + (lane >> 5) * 8;
        const float* src = gwm + l * 4096;
#pragma unroll
        for (int u = 0; u < 8; ++u) {
            float v = src[(k0 + u) * 64 + j];
            unsigned short h = rne_bf16(v);
            if (hl == 0) o[u] = h;
            else {
                float r = v - __uint_as_float((unsigned)h << 16);
                o[u] = rne_bf16(r);
            }
        }
        dst = (size_t)GMID_U4 + (l * 2 + hl) * 512 + (jt * 4 + ks) * 64 + lane;
    } else if (t < TOTAL_PK) {
        // gating out: [hl][ks(4)][lane]; 64x16, j>=16 zero-padded
        int t3 = t - GWO_U4;
        int lane = t3 & 63, ks = (t3 >> 6) & 3, hl = t3 >> 8;
        int j  = lane & 31;
        int k0 = ks * 16 + (lane >> 5) * 8;
#pragma unroll
        for (int u = 0; u < 8; ++u) {
            float v = (j < 16) ? gwo[(k0 + u) * 16 + j] : 0.0f;
            unsigned short h = rne_bf16(v);
            if (hl == 0) o[u] = h;
            else {
                float r = v - __uint_as_float((unsigned)h << 16);
                o[u] = rne_bf16(r);
            }
        }
        dst = (size_t)GWO_U4 + hl * 256 + ks * 64 + lane;
    } else return;
    uint4 v;
    v.x = (unsigned)o[0] | ((unsigned)o[1] << 16);
    v.y = (unsigned)o[2] | ((unsigned)o[3] << 16);
    v.z = (unsigned)o[4] | ((unsigned)o[5] << 16);
    v.w = (unsigned)o[6] | ((unsigned)o[7] << 16);
    *((uint4*)ws + dst) = v;
}

// one expert mid layer (128x128): W A-frags from global (L2), single-term h
__device__ __forceinline__ void expert_mid(const uint4* __restrict__ A,
                                           const float* __restrict__ bias,
                                           int lane, int g2,
                                           bf16x8 (&B)[8]) {
    bf16x8 N[8];
#pragma unroll
    for (int jt = 0; jt < 4; ++jt) {
        f32x16 acc;
#pragma unroll
        for (int qd = 0; qd < 4; ++qd) {
            const float4 bb = *(const float4*)(bias + jt * 32 + qd * 8 + g2 * 4);
            acc[4 * qd + 0] = bb.x; acc[4 * qd + 1] = bb.y;
            acc[4 * qd + 2] = bb.z; acc[4 * qd + 3] = bb.w;
        }
#pragma unroll
        for (int ks = 0; ks < 8; ++ks) {
            bf16x8 a = ldA(A + (jt * 8 + ks) * 64 + lane);
            acc = __builtin_amdgcn_mfma_f32_32x32x16_bf16(a, B[ks], acc, 0, 0, 0);
        }
#pragma unroll
        for (int p = 0; p < 2; ++p) {
            float t0 = tanh_fast(acc[8 * p + 0]), t1 = tanh_fast(acc[8 * p + 1]);
            float t2 = tanh_fast(acc[8 * p + 2]), t3 = tanh_fast(acc[8 * p + 3]);
            float t4 = tanh_fast(acc[8 * p + 4]), t5 = tanh_fast(acc[8 * p + 5]);
            float t6 = tanh_fast(acc[8 * p + 6]), t7 = tanh_fast(acc[8 * p + 7]);
            unsigned ah0 = cvt_pk(t0, t1), ah1 = cvt_pk(t2, t3);
            unsigned bh0 = cvt_pk(t4, t5), bh1 = cvt_pk(t6, t7);
            lane32_swap(ah0, bh0); lane32_swap(ah1, bh1);
            N[2 * jt + p] = mk8(ah0, ah1, bh0, bh1);
        }
    }
#pragma unroll
    for (int k = 0; k < 8; ++k) B[k] = N[k];
}

__launch_bounds__(THREADS, 4)
__global__ void moe_fused(const float* __restrict__ x,
                          const float* __restrict__ ew1,
                          const float* __restrict__ eb1,
                          const float* __restrict__ ebm,
                          const float* __restrict__ ewo,
                          const float* __restrict__ ebo,
                          const float* __restrict__ gw1,
                          const float* __restrict__ gb1,
                          const float* __restrict__ gbm,
                          const float* __restrict__ gbo,
                          const uint4* __restrict__ wsA,
                          float* __restrict__ y) {
    __shared__ float gates_s[16 * 32];   // [e][tok]
    __shared__ float eo_s[16 * 32];      // [e][tok] pre-gate expert outputs

    const int tid  = threadIdx.x;
    const int blk  = blockIdx.x;
    const int lane = tid & 63;
    const int w_id = tid >> 6;           // 0..3: expert quarter
    const int t    = lane & 31;          // token within block tile
    const int g2   = lane >> 5;
    const int gtok = blk * T_BLK + t;
    const float ex0 = x[gtok * 2 + 0];
    const float ex1 = x[gtok * 2 + 1];

    // ================= gating (wave 0 only; overlaps other waves' experts) =======
    if (w_id == 0) {
        bf16x8 Gh[4], Gl[4];
        // L1: 2 -> 64 directly in B-frag layout
#pragma unroll
        for (int ks = 0; ks < 4; ++ks) {
            int j8 = ks * 16 + g2 * 8;
            const float4 w00 = *(const float4*)(gw1 + j8);
            const float4 w01 = *(const float4*)(gw1 + j8 + 4);
            const float4 w10 = *(const float4*)(gw1 + 64 + j8);
            const float4 w11 = *(const float4*)(gw1 + 64 + j8 + 4);
            const float4 b0  = *(const float4*)(gb1 + j8);
            const float4 b1  = *(const float4*)(gb1 + j8 + 4);
            float t0 = tanh_fast(fmaf(ex0, w00.x, fmaf(ex1, w10.x, b0.x)));
            float t1 = tanh_fast(fmaf(ex0, w00.y, fmaf(ex1, w10.y, b0.y)));
            float t2 = tanh_fast(fmaf(ex0, w00.z, fmaf(ex1, w10.z, b0.z)));
            float t3 = tanh_fast(fmaf(ex0, w00.w, fmaf(ex1, w10.w, b0.w)));
            float t4 = tanh_fast(fmaf(ex0, w01.x, fmaf(ex1, w11.x, b1.x)));
            float t5 = tanh_fast(fmaf(ex0, w01.y, fmaf(ex1, w11.y, b1.y)));
            float t6 = tanh_fast(fmaf(ex0, w01.z, fmaf(ex1, w11.z, b1.z)));
            float t7 = tanh_fast(fmaf(ex0, w01.w, fmaf(ex1, w11.w, b1.w)));
            unsigned h0, l0, h1, l1, h2, l2, h3, l3;
            split_pair(t0, t1, h0, l0); split_pair(t2, t3, h1, l1);
            split_pair(t4, t5, h2, l2); split_pair(t6, t7, h3, l3);
            Gh[ks] = mk8(h0, h1, h2, h3);
            Gl[ks] = mk8(l0, l1, l2, l3);
        }
        // 2 mid layers (64x64), 3-term hi/lo MFMA
#pragma unroll
        for (int l = 0; l < 2; ++l) {
            bf16x8 NGh[4], NGl[4];
#pragma unroll
            for (int jt = 0; jt < 2; ++jt) {
                f32x16 acc;
#pragma unroll
                for (int qd = 0; qd < 4; ++qd) {
                    const float4 bb = *(const float4*)(gbm + l * 64 + jt * 32 + qd * 8 + g2 * 4);
                    acc[4 * qd + 0] = bb.x; acc[4 * qd + 1] = bb.y;
                    acc[4 * qd + 2] = bb.z; acc[4 * qd + 3] = bb.w;
                }
#pragma unroll
                for (int ks = 0; ks < 4; ++ks) {
                    bf16x8 ahi = ldA(wsA + GMID_U4 + (l * 2 + 0) * 512 + (jt * 4 + ks) * 64 + lane);
                    bf16x8 alo = ldA(wsA + GMID_U4 + (l * 2 + 1) * 512 + (jt * 4 + ks) * 64 + lane);
                    acc = __builtin_amdgcn_mfma_f32_32x32x16_bf16(ahi, Gh[ks], acc, 0, 0, 0);
                    acc = __builtin_amdgcn_mfma_f32_32x32x16_bf16(ahi, Gl[ks], acc, 0, 0, 0);
                    acc = __builtin_amdgcn_mfma_f32_32x32x16_bf16(alo, Gh[ks], acc, 0, 0, 0);
                }
                float tv[16];
#pragma unroll
                for (int r = 0; r < 16; ++r) tv[r] = tanh_fast(acc[r]);
#pragma unroll
                for (int p = 0; p < 2; ++p) {
                    unsigned ah0, al0, ah1, al1, bh0, bl0, bh1, bl1;
                    split_pair(tv[8 * p + 0], tv[8 * p + 1], ah0, al0);
                    split_pair(tv[8 * p + 2], tv[8 * p + 3], ah1, al1);
                    split_pair(tv[8 * p + 4], tv[8 * p + 5], bh0, bl0);
                    split_pair(tv[8 * p + 6], tv[8 * p + 7], bh1, bl1);
                    lane32_swap(ah0, bh0); lane32_swap(ah1, bh1);
                    lane32_swap(al0, bl0); lane32_swap(al1, bl1);
                    NGh[2 * jt + p] = mk8(ah0, ah1, bh0, bh1);
                    NGl[2 * jt + p] = mk8(al0, al1, bl0, bl1);
                }
            }
#pragma unroll
            for (int k = 0; k < 4; ++k) { Gh[k] = NGh[k]; Gl[k] = NGl[k]; }
        }
        // logits (64 -> 16) + sin -> gates LDS
        {
            f32x16 acc;
            const float4 ba = *(const float4*)(gbo + g2 * 4);
            const float4 bc = *(const float4*)(gbo + 8 + g2 * 4);
            acc[0] = ba.x; acc[1] = ba.y; acc[2] = ba.z; acc[3] = ba.w;
            acc[4] = bc.x; acc[5] = bc.y; acc[6] = bc.z; acc[7] = bc.w;
#pragma unroll
            for (int r = 8; r < 16; ++r) acc[r] = 0.0f;
#pragma unroll
            for (int ks = 0; ks < 4; ++ks) {
                bf16x8 ahi = ldA(wsA + GWO_U4 + 0 * 256 + ks * 64 + lane);
                bf16x8 alo = ldA(wsA + GWO_U4 + 1 * 256 + ks * 64 + lane);
                acc = __builtin_amdgcn_mfma_f32_32x32x16_bf16(ahi, Gh[ks], acc, 0, 0, 0);
                acc = __builtin_amdgcn_mfma_f32_32x32x16_bf16(ahi, Gl[ks], acc, 0, 0, 0);
                acc = __builtin_amdgcn_mfma_f32_32x32x16_bf16(alo, Gh[ks], acc, 0, 0, 0);
            }
            const float FIVE_PI = 15.707963267948966f;
#pragma unroll
            for (int r = 0; r < 8; ++r) {
                int e_own = (r & 3) + 8 * (r >> 2) + 4 * g2;   // row index = expert
                gates_s[e_own * 32 + t] = __sinf(FIVE_PI * acc[r]);
            }
        }
    }

    // ================= experts (4 per wave, single-term register h) =================
    bf16x8 B[8];
    const int e_begin = w_id * 4;

#pragma unroll 1
    for (int le = 0; le < 4; ++le) {
        const int e = e_begin + le;
        // ---- EL1: 2 -> 128, direct B-frag ----
        {
            const float* w1 = ew1 + e * 256;
            const float* b1 = eb1 + e * 128;
#pragma unroll
            for (int ks = 0; ks < 8; ++ks) {
                int j8 = ks * 16 + g2 * 8;
                const float4 wa0 = *(const float4*)(w1 + j8);
                const float4 wa1 = *(const float4*)(w1 + j8 + 4);
                const float4 wb0 = *(const float4*)(w1 + 128 + j8);
                const float4 wb1 = *(const float4*)(w1 + 128 + j8 + 4);
                const float4 bb0 = *(const float4*)(b1 + j8);
                const float4 bb1 = *(const float4*)(b1 + j8 + 4);
                float t0 = tanh_fast(fmaf(ex0, wa0.x, fmaf(ex1, wb0.x, bb0.x)));
                float t1 = tanh_fast(fmaf(ex0, wa0.y, fmaf(ex1, wb0.y, bb0.y)));
                float t2 = tanh_fast(fmaf(ex0, wa0.z, fmaf(ex1, wb0.z, bb0.z)));
                float t3 = tanh_fast(fmaf(ex0, wa0.w, fmaf(ex1, wb0.w, bb0.w)));
                float t4 = tanh_fast(fmaf(ex0, wa1.x, fmaf(ex1, wb1.x, bb1.x)));
                float t5 = tanh_fast(fmaf(ex0, wa1.y, fmaf(ex1, wb1.y, bb1.y)));
                float t6 = tanh_fast(fmaf(ex0, wa1.z, fmaf(ex1, wb1.z, bb1.z)));
                float t7 = tanh_fast(fmaf(ex0, wa1.w, fmaf(ex1, wb1.w, bb1.w)));
                B[ks] = mk8(cvt_pk(t0, t1), cvt_pk(t2, t3),
                            cvt_pk(t4, t5), cvt_pk(t6, t7));
            }
        }
        // ---- 3 mid layers ----
        const uint4* A = wsA + (size_t)(e * 3) * 2048;
        expert_mid(A,        ebm + (e * 3 + 0) * 128, lane, g2, B);
        expert_mid(A + 2048, ebm + (e * 3 + 1) * 128, lane, g2, B);
        expert_mid(A + 4096, ebm + (e * 3 + 2) * 128, lane, g2, B);
        // ---- output dot -> pre-gate eo into LDS ----
        {
            float ps = 0.0f;
            const float* wo = ewo + e * 128;
#pragma unroll
            for (int ks = 0; ks < 8; ++ks) {
                int j8 = ks * 16 + g2 * 8;
                const float4 w0 = *(const float4*)(wo + j8);
                const float4 w1v = *(const float4*)(wo + j8 + 4);
                union { bf16x8 v; unsigned u[4]; } H;
                H.v = B[ks];
                float e0 = __uint_as_float(H.u[0] << 16);
                float e1 = __uint_as_float(H.u[0] & 0xffff0000u);
                float e2 = __uint_as_float(H.u[1] << 16);
                float e3 = __uint_as_float(H.u[1] & 0xffff0000u);
                float e4 = __uint_as_float(H.u[2] << 16);
                float e5 = __uint_as_float(H.u[2] & 0xffff0000u);
                float e6 = __uint_as_float(H.u[3] << 16);
                float e7 = __uint_as_float(H.u[3] & 0xffff0000u);
                ps = fmaf(e0, w0.x, ps);  ps = fmaf(e1, w0.y, ps);
                ps = fmaf(e2, w0.z, ps);  ps = fmaf(e3, w0.w, ps);
                ps = fmaf(e4, w1v.x, ps); ps = fmaf(e5, w1v.y, ps);
                ps = fmaf(e6, w1v.z, ps); ps = fmaf(e7, w1v.w, ps);
            }
            ps += __shfl_xor(ps, 32, 64);
            if (g2 == 0) eo_s[e * 32 + t] = ps + ebo[e];
        }
    }

    // ================= single barrier, then gate-weighted combine =================
    __syncthreads();
    if (w_id == 0 && g2 == 0) {
        float yv = 0.0f;
#pragma unroll
        for (int e2 = 0; e2 < 16; ++e2)
            yv = fmaf(gates_s[e2 * 32 + t], eo_s[e2 * 32 + t], yv);
        y[gtok] = yv;
    }
}

extern "C" void kernel_launch(void* const* d_in, const int* in_sizes, int n_in,
                              void* d_out, int out_size, void* d_ws, size_t ws_size,
                              hipStream_t stream) {
    const float* x   = (const float*)d_in[0];
    const float* ew1 = (const float*)d_in[1];
    const float* eb1 = (const float*)d_in[2];
    const float* ewm = (const float*)d_in[3];
    const float* ebm = (const float*)d_in[4];
    const float* ewo = (const float*)d_in[5];
    const float* ebo = (const float*)d_in[6];
    const float* gw1 = (const float*)d_in[7];
    const float* gb1 = (const float*)d_in[8];
    const float* gwm = (const float*)d_in[9];
    const float* gbm = (const float*)d_in[10];
    const float* gwo = (const float*)d_in[11];
    const float* gbo = (const float*)d_in[12];
    float* y = (float*)d_out;
    unsigned short* ws = (unsigned short*)d_ws;   // 1.61 MB packed A-frags

    pack_wm_kernel<<<TOTAL_PK / 256, 256, 0, stream>>>(ewm, gwm, gwo, ws);

    moe_fused<<<dim3(N_TOK / T_BLK), dim3(THREADS), 0, stream>>>(
        x, ew1, eb1, ebm, ewo, ebo, gw1, gb1, gbm, gbo,
        (const uint4*)ws, y);
}